// Round 5
// baseline (500.114 us; speedup 1.0000x reference)
//
#include <hip/hip_runtime.h>
#include <hip/hip_bf16.h>

#define BN_EPS 1e-5f

__device__ __forceinline__ float bf2f(ushort u) {
    return __uint_as_float(((unsigned int)u) << 16);
}
__device__ __forceinline__ ushort f2bf(float f) {
    unsigned int u = __float_as_uint(f);
    u += 0x7FFFu + ((u >> 16) & 1u);
    return (ushort)(u >> 16);
}

// ---------------- degree / normalization ----------------
__global__ void k_count_deg(const int* __restrict__ dst, int E, int* __restrict__ deg) {
    int i = blockIdx.x * blockDim.x + threadIdx.x;
    if (i < E) atomicAdd(&deg[dst[i]], 1);
}

__global__ void k_dis(const int* __restrict__ deg, int n, float* __restrict__ dis) {
    int i = blockIdx.x * blockDim.x + threadIdx.x;
    if (i < n) dis[i] = rsqrtf((float)(deg[i] + 1));   // +1 self-loop
}

// ---------------- CSR build: exclusive scan of deg ----------------
__global__ void k_scanA(const int* __restrict__ deg, int n, int* __restrict__ bsum) {
    __shared__ int sh[256];
    int base = blockIdx.x * 1024 + threadIdx.x * 4;
    int s = 0;
    #pragma unroll
    for (int k = 0; k < 4; ++k) { int i = base + k; if (i < n) s += deg[i]; }
    sh[threadIdx.x] = s;
    __syncthreads();
    for (int off = 128; off > 0; off >>= 1) {
        if (threadIdx.x < off) sh[threadIdx.x] += sh[threadIdx.x + off];
        __syncthreads();
    }
    if (threadIdx.x == 0) bsum[blockIdx.x] = sh[0];
}

__global__ void k_scanB(int* __restrict__ bsum, int nb) {
    if (threadIdx.x == 0) {
        int run = 0;
        for (int i = 0; i < nb; ++i) { int v = bsum[i]; bsum[i] = run; run += v; }
    }
}

__global__ void k_scanC(const int* __restrict__ deg, const int* __restrict__ bsum,
                        int n, int E, int* __restrict__ rowptr, int* __restrict__ nextpos) {
    __shared__ int sh[256];
    int tid = threadIdx.x;
    int base = blockIdx.x * 1024 + tid * 4;
    int v[4]; int tsum = 0;
    #pragma unroll
    for (int k = 0; k < 4; ++k) {
        int i = base + k;
        v[k] = (i < n) ? deg[i] : 0;
        tsum += v[k];
    }
    sh[tid] = tsum;
    __syncthreads();
    for (int off = 1; off < 256; off <<= 1) {
        int add = (tid >= off) ? sh[tid - off] : 0;
        __syncthreads();
        sh[tid] += add;
        __syncthreads();
    }
    int excl = bsum[blockIdx.x] + sh[tid] - tsum;
    #pragma unroll
    for (int k = 0; k < 4; ++k) {
        int i = base + k;
        if (i < n) { rowptr[i] = excl; nextpos[i] = excl; }
        excl += v[k];
    }
    if (blockIdx.x == 0 && tid == 0) rowptr[n] = E;
}

// fill: cs[pos] = src  (4-byte payload; weight recomputed in gather)
__global__ void k_fill(const int* __restrict__ src, const int* __restrict__ dst,
                       int E, int* __restrict__ nextpos, int* __restrict__ cs) {
    int i = blockIdx.x * blockDim.x + threadIdx.x;
    if (i < E) {
        int d = dst[i];
        int pos = atomicAdd(&nextpos[d], 1);
        cs[pos] = src[i];
    }
}

// ---------------- tiled dense transform: tb[64-tile][64] = f(X)[64-tile][64] @ W (bf16 out) ----
__global__ void k_matmul64t(const float* __restrict__ X, const float* __restrict__ W,
                            const float* __restrict__ bnp, int n, ushort* __restrict__ tb) {
    __shared__ float Xs[64][68];
    __shared__ float Ws[64][64];
    const int tid = threadIdx.x;
    const int rowbase = blockIdx.x * 64;

    {
        const float4* W4 = (const float4*)W;
        float4* Ws4 = (float4*)&Ws[0][0];
        #pragma unroll
        for (int k = 0; k < 4; ++k) Ws4[tid + 256 * k] = W4[tid + 256 * k];
    }
    {
        const int r  = tid >> 2;
        const int c0 = (tid & 3) * 16;
        const int row = rowbase + r;
        #pragma unroll
        for (int j = 0; j < 4; ++j) {
            float4 v;
            if (row < n) v = *(const float4*)&X[(size_t)row * 64 + c0 + 4 * j];
            else v = make_float4(0.f, 0.f, 0.f, 0.f);
            float vv[4] = {v.x, v.y, v.z, v.w};
            #pragma unroll
            for (int i = 0; i < 4; ++i) {
                int c = c0 + 4 * j + i;
                float f = vv[i];
                if (bnp) f = fmaxf(0.f, fmaf(f, bnp[c], bnp[64 + c]));
                Xs[c][r] = f;
            }
        }
    }
    __syncthreads();

    const int r0 = (tid & 15) * 4;
    const int c0 = (tid >> 4) * 4;
    float acc[4][4];
    #pragma unroll
    for (int i = 0; i < 4; ++i)
        #pragma unroll
        for (int j = 0; j < 4; ++j) acc[i][j] = 0.f;

    #pragma unroll 4
    for (int k = 0; k < 64; ++k) {
        float4 xv = *(const float4*)&Xs[k][r0];
        float4 wv = *(const float4*)&Ws[k][c0];
        float xa[4] = {xv.x, xv.y, xv.z, xv.w};
        float wa[4] = {wv.x, wv.y, wv.z, wv.w};
        #pragma unroll
        for (int i = 0; i < 4; ++i)
            #pragma unroll
            for (int j = 0; j < 4; ++j)
                acc[i][j] = fmaf(xa[i], wa[j], acc[i][j]);
    }

    #pragma unroll
    for (int i = 0; i < 4; ++i) {
        int row = rowbase + r0 + i;
        if (row < n) {
            ushort4 o;
            o.x = f2bf(acc[i][0]); o.y = f2bf(acc[i][1]);
            o.z = f2bf(acc[i][2]); o.w = f2bf(acc[i][3]);
            *(ushort4*)&tb[(size_t)row * 64 + c0] = o;
        }
    }
}

// ---------------- aggregation: one wave per dst node, 4 edges/iter via quarter-waves --------
__global__ void k_gather(const int* __restrict__ cs, const int* __restrict__ rowptr,
                         const float* __restrict__ dis, const ushort* __restrict__ tb,
                         int n, float* __restrict__ a) {
    int lane = threadIdx.x & 63;
    int wave = threadIdx.x >> 6;
    int row = blockIdx.x * 4 + wave;
    if (row >= n) return;
    const int hl = lane & 15;      // feature group: features 4hl..4hl+3
    const int q  = lane >> 4;      // quarter: edge index j*4+q
    int e0 = rowptr[row], e1 = rowptr[row + 1];
    float disrow = dis[row];
    float ax = 0.f, ay = 0.f, az = 0.f, aw = 0.f;
    for (int base = e0; base < e1; base += 64) {
        int cnt = min(64, e1 - base);
        int p = (lane < cnt) ? cs[base + lane] : 0;
        int nq = (cnt + 3) >> 2;
        for (int j = 0; j < nq; ++j) {
            int idx = 4 * j + q;
            int s = __shfl(p, idx);
            float w = (idx < cnt) ? dis[s] * disrow : 0.f;
            ushort4 tv = *(const ushort4*)&tb[(size_t)s * 64 + 4 * hl];
            ax = fmaf(bf2f(tv.x), w, ax);
            ay = fmaf(bf2f(tv.y), w, ay);
            az = fmaf(bf2f(tv.z), w, az);
            aw = fmaf(bf2f(tv.w), w, aw);
        }
    }
    ax += __shfl_xor(ax, 16); ay += __shfl_xor(ay, 16);
    az += __shfl_xor(az, 16); aw += __shfl_xor(aw, 16);
    ax += __shfl_xor(ax, 32); ay += __shfl_xor(ay, 32);
    az += __shfl_xor(az, 32); aw += __shfl_xor(aw, 32);
    if (q == 0) {
        float d2 = disrow * disrow;
        ushort4 ts = *(const ushort4*)&tb[(size_t)row * 64 + 4 * hl];
        ax = fmaf(bf2f(ts.x), d2, ax);
        ay = fmaf(bf2f(ts.y), d2, ay);
        az = fmaf(bf2f(ts.z), d2, az);
        aw = fmaf(bf2f(ts.w), d2, aw);
        *(float4*)&a[(size_t)row * 64 + 4 * hl] = make_float4(ax, ay, az, aw);
    }
}

// ---------------- BatchNorm stats ----------------
__global__ void k_stats(const float* __restrict__ a, int n, float* __restrict__ stats) {
    int c = threadIdx.x & 63;
    int grp = threadIdx.x >> 6;
    float s = 0.f, s2 = 0.f;
    for (int r = blockIdx.x * 4 + grp; r < n; r += gridDim.x * 4) {
        float v = a[(size_t)r * 64 + c];
        s += v; s2 += v * v;
    }
    __shared__ float sh[2][4][64];
    sh[0][grp][c] = s; sh[1][grp][c] = s2;
    __syncthreads();
    if (threadIdx.x < 64) {
        float S  = sh[0][0][c] + sh[0][1][c] + sh[0][2][c] + sh[0][3][c];
        float S2 = sh[1][0][c] + sh[1][1][c] + sh[1][2][c] + sh[1][3][c];
        atomicAdd(&stats[c], S);
        atomicAdd(&stats[64 + c], S2);
    }
}

__global__ void k_bnparams(const float* __restrict__ stats, const float* __restrict__ g,
                           const float* __restrict__ bt, int n, float* __restrict__ bnp) {
    int c = threadIdx.x;
    if (c < 64) {
        float inv_n = 1.f / (float)n;
        float mean = stats[c] * inv_n;
        float var = stats[64 + c] * inv_n - mean * mean;
        float s = g[c] * rsqrtf(var + BN_EPS);
        bnp[c] = s;
        bnp[64 + c] = bt[c] - mean * s;
    }
}

// ---------------- global mean pool: sorted batch -> segmented reduction ----------------
__global__ void k_gbound(const int* __restrict__ batch, int n, int G, int* __restrict__ gs) {
    int g = blockIdx.x * blockDim.x + threadIdx.x;
    if (g > G) return;
    int lo = 0, hi = n;
    while (lo < hi) { int mid = (lo + hi) >> 1; if (batch[mid] < g) lo = mid + 1; else hi = mid; }
    gs[g] = lo;
}

__global__ void k_pool2(const float* __restrict__ a, const float* __restrict__ bnp,
                        const int* __restrict__ gs, int G, float* __restrict__ out) {
    int lane = threadIdx.x & 63;
    int wave = threadIdx.x >> 6;
    int g = blockIdx.x * 4 + wave;
    if (g >= G) return;
    int s = gs[g], e = gs[g + 1];
    float sc = bnp[lane], of = bnp[64 + lane];
    float acc = 0.f;
    for (int r = s; r < e; ++r)
        acc += fmaxf(0.f, fmaf(a[(size_t)r * 64 + lane], sc, of));
    out[(size_t)g * 64 + lane] = acc / (float)max(e - s, 1);
}

// ---------------- launch ----------------
extern "C" void kernel_launch(void* const* d_in, const int* in_sizes, int n_in,
                              void* d_out, int out_size, void* d_ws, size_t ws_size,
                              hipStream_t stream) {
    const float* x     = (const float*)d_in[0];
    const int*   ei    = (const int*)d_in[1];
    const int*   batch = (const int*)d_in[2];
    const float* W1    = (const float*)d_in[3];
    const float* g1    = (const float*)d_in[5];
    const float* bt1   = (const float*)d_in[6];
    const float* W2    = (const float*)d_in[7];
    const float* g2    = (const float*)d_in[9];
    const float* bt2   = (const float*)d_in[10];

    const int N = in_sizes[0] / 64;
    const int E = in_sizes[1] / 2;
    const int G = out_size / 64;

    const int* src = ei;
    const int* dst = ei + E;

    ushort* tb     = (ushort*)d_ws;                     // N*64 bf16
    float* a       = (float*)(tb + (size_t)N * 64);     // N*64 f32
    int*   cs      = (int*)(a + (size_t)N * 64);        // E
    float* dis     = (float*)(cs + E);                  // N
    int*   deg     = (int*)(dis + N);                   // N
    int*   rowptr  = deg + N;                           // N+1
    int*   nextpos = rowptr + N + 1;                    // N
    int*   bsum    = nextpos + N;                       // <=1024
    float* stats   = (float*)(bsum + 1024);             // 128
    float* bnp     = stats + 128;                       // 128
    int*   gs      = (int*)(bnp + 128);                 // G+1

    float* out = (float*)d_out;

    const int NBLK = (N + 1023) / 1024;
    const int mmBlocks = (N + 63) / 64;
    const int gaBlocks = (N + 3) / 4;

    // ---- degree / norm / CSR build / graph bounds ----
    hipMemsetAsync(deg, 0, (size_t)N * sizeof(int), stream);
    k_count_deg<<<(E + 255) / 256, 256, 0, stream>>>(dst, E, deg);
    k_dis<<<(N + 255) / 256, 256, 0, stream>>>(deg, N, dis);
    k_scanA<<<NBLK, 256, 0, stream>>>(deg, N, bsum);
    k_scanB<<<1, 64, 0, stream>>>(bsum, NBLK);
    k_scanC<<<NBLK, 256, 0, stream>>>(deg, bsum, N, E, rowptr, nextpos);
    k_fill<<<(E + 255) / 256, 256, 0, stream>>>(src, dst, E, nextpos, cs);
    k_gbound<<<(G + 256) / 256, 256, 0, stream>>>(batch, N, G, gs);

    // ---- layer 1 ----
    k_matmul64t<<<mmBlocks, 256, 0, stream>>>(x, W1, nullptr, N, tb);
    k_gather<<<gaBlocks, 256, 0, stream>>>(cs, rowptr, dis, tb, N, a);
    hipMemsetAsync(stats, 0, 128 * sizeof(float), stream);
    k_stats<<<512, 256, 0, stream>>>(a, N, stats);
    k_bnparams<<<1, 64, 0, stream>>>(stats, g1, bt1, N, bnp);

    // ---- layer 2 (BN+ReLU of layer 1 fused into matmul input) ----
    k_matmul64t<<<mmBlocks, 256, 0, stream>>>(a, W2, bnp, N, tb);
    k_gather<<<gaBlocks, 256, 0, stream>>>(cs, rowptr, dis, tb, N, a);
    hipMemsetAsync(stats, 0, 128 * sizeof(float), stream);
    k_stats<<<512, 256, 0, stream>>>(a, N, stats);
    k_bnparams<<<1, 64, 0, stream>>>(stats, g2, bt2, N, bnp);

    // ---- pool (BN+ReLU of layer 2 fused) ----
    k_pool2<<<(G + 3) / 4, 256, 0, stream>>>(a, bnp, gs, G, out);
}

// Round 6
// 338.653 us; speedup vs baseline: 1.4768x; 1.4768x over previous
//
#include <hip/hip_runtime.h>
#include <hip/hip_bf16.h>

#define BN_EPS 1e-5f
#define CCHUNK 8192    // edges per partition block

__device__ __forceinline__ float bf2f(ushort u) {
    return __uint_as_float(((unsigned int)u) << 16);
}
__device__ __forceinline__ ushort f2bf(float f) {
    unsigned int u = __float_as_uint(f);
    u += 0x7FFFu + ((u >> 16) & 1u);
    return (ushort)(u >> 16);
}

// ---------------- bucket histogram (buckets of 128 dst nodes) ----------------
__global__ void k_bhist(const int* __restrict__ dst, int E, int nb, int* __restrict__ bktcnt) {
    __shared__ int lh[1024];
    for (int j = threadIdx.x; j < nb; j += 256) lh[j] = 0;
    __syncthreads();
    for (int i = blockIdx.x * blockDim.x + threadIdx.x; i < E; i += gridDim.x * blockDim.x)
        atomicAdd(&lh[dst[i] >> 7], 1);
    __syncthreads();
    for (int j = threadIdx.x; j < nb; j += 256) {
        int c = lh[j];
        if (c) atomicAdd(&bktcnt[j], c);
    }
}

// ---------------- single-block exclusive scan of bucket counts ----------------
__global__ void k_bscan(const int* __restrict__ bktcnt, int nb, int N,
                        int* __restrict__ bktoff, int* __restrict__ gpos,
                        int* __restrict__ rowptr) {
    __shared__ int sh[256];
    int tid = threadIdx.x;
    int base = tid * 4;
    int v[4]; int tsum = 0;
    #pragma unroll
    for (int k = 0; k < 4; ++k) {
        int i = base + k;
        v[k] = (i < nb) ? bktcnt[i] : 0;
        tsum += v[k];
    }
    sh[tid] = tsum;
    __syncthreads();
    for (int off = 1; off < 256; off <<= 1) {
        int add = (tid >= off) ? sh[tid - off] : 0;
        __syncthreads();
        sh[tid] += add;
        __syncthreads();
    }
    int excl = sh[tid] - tsum;
    #pragma unroll
    for (int k = 0; k < 4; ++k) {
        int i = base + k;
        if (i <= nb) {
            bktoff[i] = excl;
            if (i < nb) gpos[i] = excl;
        }
        excl += v[k];
    }
    if (tid == 255) rowptr[N] = sh[255];   // total = E
}

// ---------------- partition edges into bucket-contiguous order (block-aggregated) ----------
__global__ void k_partition(const int* __restrict__ src, const int* __restrict__ dst,
                            int E, int nb, int sb,
                            int* __restrict__ gpos, unsigned int* __restrict__ eb) {
    __shared__ int lh[1024];
    int e0 = blockIdx.x * CCHUNK;
    int cnt = min(CCHUNK, E - e0);
    for (int j = threadIdx.x; j < nb; j += 256) lh[j] = 0;
    __syncthreads();
    for (int k = threadIdx.x; k < cnt; k += 256)
        atomicAdd(&lh[dst[e0 + k] >> 7], 1);
    __syncthreads();
    for (int j = threadIdx.x; j < nb; j += 256) {
        int c = lh[j];
        if (c) lh[j] = atomicAdd(&gpos[j], c);   // reserve contiguous run, lh becomes cursor
    }
    __syncthreads();
    for (int k = threadIdx.x; k < cnt; k += 256) {
        int d = dst[e0 + k];
        unsigned int s = (unsigned int)src[e0 + k];
        int pos = atomicAdd(&lh[d >> 7], 1);
        eb[pos] = (((unsigned int)(d & 127)) << sb) | s;
    }
}

// ---------------- per-bucket: deg -> rowptr + dis (LDS hist + scan) ----------------
__global__ void k_row(const unsigned int* __restrict__ eb, const int* __restrict__ bktoff,
                      int sb, int N, float* __restrict__ dis, int* __restrict__ rowptr) {
    __shared__ int h[128];
    __shared__ int p[128];
    int tid = threadIdx.x;
    int b = blockIdx.x;
    if (tid < 128) h[tid] = 0;
    __syncthreads();
    int e0 = bktoff[b], e1 = bktoff[b + 1];
    for (int e = e0 + tid; e < e1; e += 256)
        atomicAdd(&h[(eb[e] >> sb) & 127], 1);
    __syncthreads();
    if (tid < 128) p[tid] = h[tid];
    __syncthreads();
    for (int off = 1; off < 128; off <<= 1) {
        int add = (tid < 128 && tid >= off) ? p[tid - off] : 0;
        __syncthreads();
        if (tid < 128) p[tid] += add;
        __syncthreads();
    }
    if (tid < 128) {
        int d = b * 128 + tid;
        if (d < N) {
            rowptr[d] = e0 + p[tid] - h[tid];
            dis[d] = rsqrtf((float)(h[tid] + 1));   // +1 self-loop
        }
    }
}

// ---------------- per-bucket CSR fill (writes confined to one L2) ----------------
__global__ void k_csrfill(const unsigned int* __restrict__ eb, const int* __restrict__ bktoff,
                          const int* __restrict__ rowptr, int sb, unsigned int smask,
                          int N, int* __restrict__ cs) {
    __shared__ int nc[128];
    int tid = threadIdx.x;
    int b = blockIdx.x;
    if (tid < 128) {
        int d = b * 128 + tid;
        nc[tid] = (d < N) ? rowptr[d] : 0;
    }
    __syncthreads();
    int e0 = bktoff[b], e1 = bktoff[b + 1];
    for (int e = e0 + tid; e < e1; e += 256) {
        unsigned int v = eb[e];
        int dl = (v >> sb) & 127;
        int slot = atomicAdd(&nc[dl], 1);
        cs[slot] = (int)(v & smask);
    }
}

// ---------------- tiled dense transform: tb[64-tile][64] = f(X)[64-tile][64] @ W (bf16 out) ----
__global__ void k_matmul64t(const float* __restrict__ X, const float* __restrict__ W,
                            const float* __restrict__ bnp, int n, ushort* __restrict__ tb) {
    __shared__ float Xs[64][68];
    __shared__ float Ws[64][64];
    const int tid = threadIdx.x;
    const int rowbase = blockIdx.x * 64;

    {
        const float4* W4 = (const float4*)W;
        float4* Ws4 = (float4*)&Ws[0][0];
        #pragma unroll
        for (int k = 0; k < 4; ++k) Ws4[tid + 256 * k] = W4[tid + 256 * k];
    }
    {
        const int r  = tid >> 2;
        const int c0 = (tid & 3) * 16;
        const int row = rowbase + r;
        #pragma unroll
        for (int j = 0; j < 4; ++j) {
            float4 v;
            if (row < n) v = *(const float4*)&X[(size_t)row * 64 + c0 + 4 * j];
            else v = make_float4(0.f, 0.f, 0.f, 0.f);
            float vv[4] = {v.x, v.y, v.z, v.w};
            #pragma unroll
            for (int i = 0; i < 4; ++i) {
                int c = c0 + 4 * j + i;
                float f = vv[i];
                if (bnp) f = fmaxf(0.f, fmaf(f, bnp[c], bnp[64 + c]));
                Xs[c][r] = f;
            }
        }
    }
    __syncthreads();

    const int r0 = (tid & 15) * 4;
    const int c0 = (tid >> 4) * 4;
    float acc[4][4];
    #pragma unroll
    for (int i = 0; i < 4; ++i)
        #pragma unroll
        for (int j = 0; j < 4; ++j) acc[i][j] = 0.f;

    #pragma unroll 4
    for (int k = 0; k < 64; ++k) {
        float4 xv = *(const float4*)&Xs[k][r0];
        float4 wv = *(const float4*)&Ws[k][c0];
        float xa[4] = {xv.x, xv.y, xv.z, xv.w};
        float wa[4] = {wv.x, wv.y, wv.z, wv.w};
        #pragma unroll
        for (int i = 0; i < 4; ++i)
            #pragma unroll
            for (int j = 0; j < 4; ++j)
                acc[i][j] = fmaf(xa[i], wa[j], acc[i][j]);
    }

    #pragma unroll
    for (int i = 0; i < 4; ++i) {
        int row = rowbase + r0 + i;
        if (row < n) {
            ushort4 o;
            o.x = f2bf(acc[i][0]); o.y = f2bf(acc[i][1]);
            o.z = f2bf(acc[i][2]); o.w = f2bf(acc[i][3]);
            *(ushort4*)&tb[(size_t)row * 64 + c0] = o;
        }
    }
}

// ---------------- aggregation: one wave per dst node, 4 edges/iter via quarter-waves --------
__global__ void k_gather(const int* __restrict__ cs, const int* __restrict__ rowptr,
                         const float* __restrict__ dis, const ushort* __restrict__ tb,
                         int n, float* __restrict__ a) {
    int lane = threadIdx.x & 63;
    int wave = threadIdx.x >> 6;
    int row = blockIdx.x * 4 + wave;
    if (row >= n) return;
    const int hl = lane & 15;
    const int q  = lane >> 4;
    int e0 = rowptr[row], e1 = rowptr[row + 1];
    float disrow = dis[row];
    float ax = 0.f, ay = 0.f, az = 0.f, aw = 0.f;
    for (int base = e0; base < e1; base += 64) {
        int cnt = min(64, e1 - base);
        int p = (lane < cnt) ? cs[base + lane] : 0;
        int nq = (cnt + 3) >> 2;
        for (int j = 0; j < nq; ++j) {
            int idx = 4 * j + q;
            int s = __shfl(p, idx);
            float w = (idx < cnt) ? dis[s] * disrow : 0.f;
            ushort4 tv = *(const ushort4*)&tb[(size_t)s * 64 + 4 * hl];
            ax = fmaf(bf2f(tv.x), w, ax);
            ay = fmaf(bf2f(tv.y), w, ay);
            az = fmaf(bf2f(tv.z), w, az);
            aw = fmaf(bf2f(tv.w), w, aw);
        }
    }
    ax += __shfl_xor(ax, 16); ay += __shfl_xor(ay, 16);
    az += __shfl_xor(az, 16); aw += __shfl_xor(aw, 16);
    ax += __shfl_xor(ax, 32); ay += __shfl_xor(ay, 32);
    az += __shfl_xor(az, 32); aw += __shfl_xor(aw, 32);
    if (q == 0) {
        float d2 = disrow * disrow;
        ushort4 ts = *(const ushort4*)&tb[(size_t)row * 64 + 4 * hl];
        ax = fmaf(bf2f(ts.x), d2, ax);
        ay = fmaf(bf2f(ts.y), d2, ay);
        az = fmaf(bf2f(ts.z), d2, az);
        aw = fmaf(bf2f(ts.w), d2, aw);
        *(float4*)&a[(size_t)row * 64 + 4 * hl] = make_float4(ax, ay, az, aw);
    }
}

// ---------------- BatchNorm stats ----------------
__global__ void k_stats(const float* __restrict__ a, int n, float* __restrict__ stats) {
    int c = threadIdx.x & 63;
    int grp = threadIdx.x >> 6;
    float s = 0.f, s2 = 0.f;
    for (int r = blockIdx.x * 4 + grp; r < n; r += gridDim.x * 4) {
        float v = a[(size_t)r * 64 + c];
        s += v; s2 += v * v;
    }
    __shared__ float sh[2][4][64];
    sh[0][grp][c] = s; sh[1][grp][c] = s2;
    __syncthreads();
    if (threadIdx.x < 64) {
        float S  = sh[0][0][c] + sh[0][1][c] + sh[0][2][c] + sh[0][3][c];
        float S2 = sh[1][0][c] + sh[1][1][c] + sh[1][2][c] + sh[1][3][c];
        atomicAdd(&stats[c], S);
        atomicAdd(&stats[64 + c], S2);
    }
}

__global__ void k_bnparams(const float* __restrict__ stats, const float* __restrict__ g,
                           const float* __restrict__ bt, int n, float* __restrict__ bnp) {
    int c = threadIdx.x;
    if (c < 64) {
        float inv_n = 1.f / (float)n;
        float mean = stats[c] * inv_n;
        float var = stats[64 + c] * inv_n - mean * mean;
        float s = g[c] * rsqrtf(var + BN_EPS);
        bnp[c] = s;
        bnp[64 + c] = bt[c] - mean * s;
    }
}

// ---------------- global mean pool: sorted batch -> segmented reduction ----------------
__global__ void k_gbound(const int* __restrict__ batch, int n, int G, int* __restrict__ gs) {
    int g = blockIdx.x * blockDim.x + threadIdx.x;
    if (g > G) return;
    int lo = 0, hi = n;
    while (lo < hi) { int mid = (lo + hi) >> 1; if (batch[mid] < g) lo = mid + 1; else hi = mid; }
    gs[g] = lo;
}

__global__ void k_pool2(const float* __restrict__ a, const float* __restrict__ bnp,
                        const int* __restrict__ gs, int G, float* __restrict__ out) {
    int lane = threadIdx.x & 63;
    int wave = threadIdx.x >> 6;
    int g = blockIdx.x * 4 + wave;
    if (g >= G) return;
    int s = gs[g], e = gs[g + 1];
    float sc = bnp[lane], of = bnp[64 + lane];
    float acc = 0.f;
    for (int r = s; r < e; ++r)
        acc += fmaxf(0.f, fmaf(a[(size_t)r * 64 + lane], sc, of));
    out[(size_t)g * 64 + lane] = acc / (float)max(e - s, 1);
}

// ---------------- launch ----------------
extern "C" void kernel_launch(void* const* d_in, const int* in_sizes, int n_in,
                              void* d_out, int out_size, void* d_ws, size_t ws_size,
                              hipStream_t stream) {
    const float* x     = (const float*)d_in[0];
    const int*   ei    = (const int*)d_in[1];
    const int*   batch = (const int*)d_in[2];
    const float* W1    = (const float*)d_in[3];
    const float* g1    = (const float*)d_in[5];
    const float* bt1   = (const float*)d_in[6];
    const float* W2    = (const float*)d_in[7];
    const float* g2    = (const float*)d_in[9];
    const float* bt2   = (const float*)d_in[10];

    const int N = in_sizes[0] / 64;
    const int E = in_sizes[1] / 2;
    const int G = out_size / 64;

    const int* src = ei;
    const int* dst = ei + E;

    const int nb = (N + 127) >> 7;           // buckets of 128 dst nodes (requires nb <= 1024)
    int sb = 0; while ((1 << sb) < N) ++sb;  // bits to hold src id
    const unsigned int smask = (1u << sb) - 1u;

    ushort* tb        = (ushort*)d_ws;                       // N*64 bf16
    float* a          = (float*)(tb + (size_t)N * 64);       // N*64 f32
    int*   cs         = (int*)(a + (size_t)N * 64);          // E (CSR src ids)
    unsigned int* eb  = (unsigned int*)(cs + E);             // E (bucketed packed edges)
    float* dis        = (float*)(eb + E);                    // N
    int*   rowptr     = (int*)(dis + N);                     // N+1
    int*   bktcnt     = rowptr + N + 1;                      // nb
    int*   bktoff     = bktcnt + nb;                         // nb+1
    int*   gpos       = bktoff + nb + 1;                     // nb
    float* stats      = (float*)(gpos + nb);                 // 128
    float* bnp        = stats + 128;                         // 128
    int*   gs         = (int*)(bnp + 128);                   // G+1

    float* out = (float*)d_out;

    const int mmBlocks = (N + 63) / 64;
    const int gaBlocks = (N + 3) / 4;
    const int pcBlocks = (E + CCHUNK - 1) / CCHUNK;

    // ---- CSR build (bucketed, write-local) ----
    hipMemsetAsync(bktcnt, 0, (size_t)nb * sizeof(int), stream);
    k_bhist<<<256, 256, 0, stream>>>(dst, E, nb, bktcnt);
    k_bscan<<<1, 256, 0, stream>>>(bktcnt, nb, N, bktoff, gpos, rowptr);
    k_partition<<<pcBlocks, 256, 0, stream>>>(src, dst, E, nb, sb, gpos, eb);
    k_row<<<nb, 256, 0, stream>>>(eb, bktoff, sb, N, dis, rowptr);
    k_csrfill<<<nb, 256, 0, stream>>>(eb, bktoff, rowptr, sb, smask, N, cs);
    k_gbound<<<(G + 256) / 256, 256, 0, stream>>>(batch, N, G, gs);

    // ---- layer 1 ----
    k_matmul64t<<<mmBlocks, 256, 0, stream>>>(x, W1, nullptr, N, tb);
    k_gather<<<gaBlocks, 256, 0, stream>>>(cs, rowptr, dis, tb, N, a);
    hipMemsetAsync(stats, 0, 128 * sizeof(float), stream);
    k_stats<<<512, 256, 0, stream>>>(a, N, stats);
    k_bnparams<<<1, 64, 0, stream>>>(stats, g1, bt1, N, bnp);

    // ---- layer 2 (BN+ReLU of layer 1 fused into matmul input) ----
    k_matmul64t<<<mmBlocks, 256, 0, stream>>>(a, W2, bnp, N, tb);
    k_gather<<<gaBlocks, 256, 0, stream>>>(cs, rowptr, dis, tb, N, a);
    hipMemsetAsync(stats, 0, 128 * sizeof(float), stream);
    k_stats<<<512, 256, 0, stream>>>(a, N, stats);
    k_bnparams<<<1, 64, 0, stream>>>(stats, g2, bt2, N, bnp);

    // ---- pool (BN+ReLU of layer 2 fused) ----
    k_pool2<<<(G + 3) / 4, 256, 0, stream>>>(a, bnp, gs, G, out);
}

// Round 8
// 303.998 us; speedup vs baseline: 1.6451x; 1.1140x over previous
//
#include <hip/hip_runtime.h>
#include <hip/hip_bf16.h>

#define BN_EPS 1e-5f
#define CCHUNK 8192    // edges per partition block

__device__ __forceinline__ float bf2f(ushort u) {
    return __uint_as_float(((unsigned int)u) << 16);
}
__device__ __forceinline__ ushort f2bf(float f) {
    unsigned int u = __float_as_uint(f);
    u += 0x7FFFu + ((u >> 16) & 1u);
    return (ushort)(u >> 16);
}

// ---------------- bucket histogram (buckets of 128 dst nodes) ----------------
__global__ void k_bhist(const int* __restrict__ dst, int E, int nb, int* __restrict__ bktcnt) {
    __shared__ int lh[1024];
    for (int j = threadIdx.x; j < nb; j += 256) lh[j] = 0;
    __syncthreads();
    for (int i = blockIdx.x * blockDim.x + threadIdx.x; i < E; i += gridDim.x * blockDim.x)
        atomicAdd(&lh[dst[i] >> 7], 1);
    __syncthreads();
    for (int j = threadIdx.x; j < nb; j += 256) {
        int c = lh[j];
        if (c) atomicAdd(&bktcnt[j], c);
    }
}

// ---------------- single-block exclusive scan of bucket counts ----------------
__global__ void k_bscan(const int* __restrict__ bktcnt, int nb, int N,
                        int* __restrict__ bktoff, int* __restrict__ gpos,
                        int* __restrict__ rowptr) {
    __shared__ int sh[256];
    int tid = threadIdx.x;
    int base = tid * 4;
    int v[4]; int tsum = 0;
    #pragma unroll
    for (int k = 0; k < 4; ++k) {
        int i = base + k;
        v[k] = (i < nb) ? bktcnt[i] : 0;
        tsum += v[k];
    }
    sh[tid] = tsum;
    __syncthreads();
    for (int off = 1; off < 256; off <<= 1) {
        int add = (tid >= off) ? sh[tid - off] : 0;
        __syncthreads();
        sh[tid] += add;
        __syncthreads();
    }
    int excl = sh[tid] - tsum;
    #pragma unroll
    for (int k = 0; k < 4; ++k) {
        int i = base + k;
        if (i <= nb) {
            bktoff[i] = excl;
            if (i < nb) gpos[i] = excl;
        }
        excl += v[k];
    }
    if (tid == 255) rowptr[N] = sh[255];   // total = E
}

// ---------------- partition edges into bucket-contiguous order ----------------
__global__ void k_partition(const int* __restrict__ src, const int* __restrict__ dst,
                            int E, int nb, int sb,
                            int* __restrict__ gpos, unsigned int* __restrict__ eb) {
    __shared__ int lh[1024];
    int e0 = blockIdx.x * CCHUNK;
    int cnt = min(CCHUNK, E - e0);
    for (int j = threadIdx.x; j < nb; j += 256) lh[j] = 0;
    __syncthreads();
    for (int k = threadIdx.x; k < cnt; k += 256)
        atomicAdd(&lh[dst[e0 + k] >> 7], 1);
    __syncthreads();
    for (int j = threadIdx.x; j < nb; j += 256) {
        int c = lh[j];
        if (c) lh[j] = atomicAdd(&gpos[j], c);   // reserve contiguous run, lh becomes cursor
    }
    __syncthreads();
    for (int k = threadIdx.x; k < cnt; k += 256) {
        int d = dst[e0 + k];
        unsigned int s = (unsigned int)src[e0 + k];
        int pos = atomicAdd(&lh[d >> 7], 1);
        eb[pos] = (((unsigned int)(d & 127)) << sb) | s;
    }
}

// ---------------- per-bucket: deg -> rowptr + dis (LDS hist + scan) ----------------
__global__ void k_row(const unsigned int* __restrict__ eb, const int* __restrict__ bktoff,
                      int sb, int N, float* __restrict__ dis, int* __restrict__ rowptr) {
    __shared__ int h[128];
    __shared__ int p[128];
    int tid = threadIdx.x;
    int b = blockIdx.x;
    if (tid < 128) h[tid] = 0;
    __syncthreads();
    int e0 = bktoff[b], e1 = bktoff[b + 1];
    for (int e = e0 + tid; e < e1; e += 256)
        atomicAdd(&h[(eb[e] >> sb) & 127], 1);
    __syncthreads();
    if (tid < 128) p[tid] = h[tid];
    __syncthreads();
    for (int off = 1; off < 128; off <<= 1) {
        int add = (tid < 128 && tid >= off) ? p[tid - off] : 0;
        __syncthreads();
        if (tid < 128) p[tid] += add;
        __syncthreads();
    }
    if (tid < 128) {
        int d = b * 128 + tid;
        if (d < N) {
            rowptr[d] = e0 + p[tid] - h[tid];
            dis[d] = rsqrtf((float)(h[tid] + 1));   // +1 self-loop
        }
    }
}

// ---------------- per-bucket CSR fill + f32 edge weights ----------------
__global__ void k_csrfill(const unsigned int* __restrict__ eb, const int* __restrict__ bktoff,
                          const int* __restrict__ rowptr, const float* __restrict__ dis,
                          int sb, unsigned int smask, int N,
                          int* __restrict__ cs, float* __restrict__ wf) {
    __shared__ int nc[128];
    __shared__ float dl[128];
    int tid = threadIdx.x;
    int b = blockIdx.x;
    if (tid < 128) {
        int d = b * 128 + tid;
        nc[tid] = (d < N) ? rowptr[d] : 0;
        dl[tid] = (d < N) ? dis[d] : 1.f;
    }
    __syncthreads();
    int e0 = bktoff[b], e1 = bktoff[b + 1];
    for (int e = e0 + tid; e < e1; e += 256) {
        unsigned int v = eb[e];
        int dloc = (v >> sb) & 127;
        int s = (int)(v & smask);
        int slot = atomicAdd(&nc[dloc], 1);
        cs[slot] = s;
        wf[slot] = dis[s] * dl[dloc];
    }
}

// ---------------- tiled dense transform: tb = f(X) @ W (bf16 out) ----------------
__global__ void k_matmul64t(const float* __restrict__ X, const float* __restrict__ W,
                            const float* __restrict__ bnp, int n, ushort* __restrict__ tb) {
    __shared__ float Xs[64][68];
    __shared__ float Ws[64][64];
    const int tid = threadIdx.x;
    const int rowbase = blockIdx.x * 64;

    {
        const float4* W4 = (const float4*)W;
        float4* Ws4 = (float4*)&Ws[0][0];
        #pragma unroll
        for (int k = 0; k < 4; ++k) Ws4[tid + 256 * k] = W4[tid + 256 * k];
    }
    {
        const int r  = tid >> 2;
        const int c0 = (tid & 3) * 16;
        const int row = rowbase + r;
        #pragma unroll
        for (int j = 0; j < 4; ++j) {
            float4 v;
            if (row < n) v = *(const float4*)&X[(size_t)row * 64 + c0 + 4 * j];
            else v = make_float4(0.f, 0.f, 0.f, 0.f);
            float vv[4] = {v.x, v.y, v.z, v.w};
            #pragma unroll
            for (int i = 0; i < 4; ++i) {
                int c = c0 + 4 * j + i;
                float f = vv[i];
                if (bnp) f = fmaxf(0.f, fmaf(f, bnp[c], bnp[64 + c]));
                Xs[c][r] = f;
            }
        }
    }
    __syncthreads();

    const int r0 = (tid & 15) * 4;
    const int c0 = (tid >> 4) * 4;
    float acc[4][4];
    #pragma unroll
    for (int i = 0; i < 4; ++i)
        #pragma unroll
        for (int j = 0; j < 4; ++j) acc[i][j] = 0.f;

    #pragma unroll 4
    for (int k = 0; k < 64; ++k) {
        float4 xv = *(const float4*)&Xs[k][r0];
        float4 wv = *(const float4*)&Ws[k][c0];
        float xa[4] = {xv.x, xv.y, xv.z, xv.w};
        float wa[4] = {wv.x, wv.y, wv.z, wv.w};
        #pragma unroll
        for (int i = 0; i < 4; ++i)
            #pragma unroll
            for (int j = 0; j < 4; ++j)
                acc[i][j] = fmaf(xa[i], wa[j], acc[i][j]);
    }

    #pragma unroll
    for (int i = 0; i < 4; ++i) {
        int row = rowbase + r0 + i;
        if (row < n) {
            ushort4 o;
            o.x = f2bf(acc[i][0]); o.y = f2bf(acc[i][1]);
            o.z = f2bf(acc[i][2]); o.w = f2bf(acc[i][3]);
            *(ushort4*)&tb[(size_t)row * 64 + c0] = o;
        }
    }
}

// ---------------- aggregation: one wave per dst node, 8 edges/iter via 8-lane groups -------
__global__ void k_gather(const int* __restrict__ cs, const float* __restrict__ wf,
                         const int* __restrict__ rowptr, const float* __restrict__ dis,
                         const ushort* __restrict__ tb, int n, float* __restrict__ a) {
    int lane = threadIdx.x & 63;
    int wave = threadIdx.x >> 6;
    int row = blockIdx.x * 4 + wave;
    if (row >= n) return;
    const int fl = lane & 7;    // feature block: features 8fl..8fl+7
    const int o  = lane >> 3;   // group: edge index j*8+o
    int e0 = rowptr[row], e1 = rowptr[row + 1];
    float acc[8];
    #pragma unroll
    for (int i = 0; i < 8; ++i) acc[i] = 0.f;
    for (int base = e0; base < e1; base += 64) {
        int cnt = min(64, e1 - base);
        int   p  = (lane < cnt) ? cs[base + lane] : 0;
        float wv = (lane < cnt) ? wf[base + lane] : 0.f;
        int nq = (cnt + 7) >> 3;
        for (int j = 0; j < nq; ++j) {
            int idx = 8 * j + o;
            int s = __shfl(p, idx);
            float w = __shfl(wv, idx);          // zero beyond cnt
            uint4 tv = *(const uint4*)&tb[(size_t)s * 64 + 8 * fl];
            acc[0] = fmaf(__uint_as_float(tv.x << 16),         w, acc[0]);
            acc[1] = fmaf(__uint_as_float(tv.x & 0xffff0000u), w, acc[1]);
            acc[2] = fmaf(__uint_as_float(tv.y << 16),         w, acc[2]);
            acc[3] = fmaf(__uint_as_float(tv.y & 0xffff0000u), w, acc[3]);
            acc[4] = fmaf(__uint_as_float(tv.z << 16),         w, acc[4]);
            acc[5] = fmaf(__uint_as_float(tv.z & 0xffff0000u), w, acc[5]);
            acc[6] = fmaf(__uint_as_float(tv.w << 16),         w, acc[6]);
            acc[7] = fmaf(__uint_as_float(tv.w & 0xffff0000u), w, acc[7]);
        }
    }
    #pragma unroll
    for (int i = 0; i < 8; ++i) {
        acc[i] += __shfl_xor(acc[i], 8);
        acc[i] += __shfl_xor(acc[i], 16);
        acc[i] += __shfl_xor(acc[i], 32);
    }
    if (o == 0) {
        float dr = dis[row];
        float d2 = dr * dr;
        uint4 ts = *(const uint4*)&tb[(size_t)row * 64 + 8 * fl];
        acc[0] = fmaf(__uint_as_float(ts.x << 16),         d2, acc[0]);
        acc[1] = fmaf(__uint_as_float(ts.x & 0xffff0000u), d2, acc[1]);
        acc[2] = fmaf(__uint_as_float(ts.y << 16),         d2, acc[2]);
        acc[3] = fmaf(__uint_as_float(ts.y & 0xffff0000u), d2, acc[3]);
        acc[4] = fmaf(__uint_as_float(ts.z << 16),         d2, acc[4]);
        acc[5] = fmaf(__uint_as_float(ts.z & 0xffff0000u), d2, acc[5]);
        acc[6] = fmaf(__uint_as_float(ts.w << 16),         d2, acc[6]);
        acc[7] = fmaf(__uint_as_float(ts.w & 0xffff0000u), d2, acc[7]);
        float4 o0 = make_float4(acc[0], acc[1], acc[2], acc[3]);
        float4 o1 = make_float4(acc[4], acc[5], acc[6], acc[7]);
        *(float4*)&a[(size_t)row * 64 + 8 * fl]     = o0;
        *(float4*)&a[(size_t)row * 64 + 8 * fl + 4] = o1;
    }
}

// ---------------- BatchNorm stats ----------------
__global__ void k_stats(const float* __restrict__ a, int n, float* __restrict__ stats) {
    int c = threadIdx.x & 63;
    int grp = threadIdx.x >> 6;
    float s = 0.f, s2 = 0.f;
    for (int r = blockIdx.x * 4 + grp; r < n; r += gridDim.x * 4) {
        float v = a[(size_t)r * 64 + c];
        s += v; s2 += v * v;
    }
    __shared__ float sh[2][4][64];
    sh[0][grp][c] = s; sh[1][grp][c] = s2;
    __syncthreads();
    if (threadIdx.x < 64) {
        float S  = sh[0][0][c] + sh[0][1][c] + sh[0][2][c] + sh[0][3][c];
        float S2 = sh[1][0][c] + sh[1][1][c] + sh[1][2][c] + sh[1][3][c];
        atomicAdd(&stats[c], S);
        atomicAdd(&stats[64 + c], S2);
    }
}

__global__ void k_bnparams(const float* __restrict__ stats, const float* __restrict__ g,
                           const float* __restrict__ bt, int n, float* __restrict__ bnp) {
    int c = threadIdx.x;
    if (c < 64) {
        float inv_n = 1.f / (float)n;
        float mean = stats[c] * inv_n;
        float var = stats[64 + c] * inv_n - mean * mean;
        float s = g[c] * rsqrtf(var + BN_EPS);
        bnp[c] = s;
        bnp[64 + c] = bt[c] - mean * s;
    }
}

// ---------------- global mean pool: sorted batch -> segmented reduction ----------------
__global__ void k_gbound(const int* __restrict__ batch, int n, int G, int* __restrict__ gs) {
    int g = blockIdx.x * blockDim.x + threadIdx.x;
    if (g > G) return;
    int lo = 0, hi = n;
    while (lo < hi) { int mid = (lo + hi) >> 1; if (batch[mid] < g) lo = mid + 1; else hi = mid; }
    gs[g] = lo;
}

__global__ void k_pool2(const float* __restrict__ a, const float* __restrict__ bnp,
                        const int* __restrict__ gs, int G, float* __restrict__ out) {
    int lane = threadIdx.x & 63;
    int wave = threadIdx.x >> 6;
    int g = blockIdx.x * 4 + wave;
    if (g >= G) return;
    int s = gs[g], e = gs[g + 1];
    float sc = bnp[lane], of = bnp[64 + lane];
    float acc = 0.f;
    for (int r = s; r < e; ++r)
        acc += fmaxf(0.f, fmaf(a[(size_t)r * 64 + lane], sc, of));
    out[(size_t)g * 64 + lane] = acc / (float)max(e - s, 1);
}

// ---------------- launch ----------------
extern "C" void kernel_launch(void* const* d_in, const int* in_sizes, int n_in,
                              void* d_out, int out_size, void* d_ws, size_t ws_size,
                              hipStream_t stream) {
    const float* x     = (const float*)d_in[0];
    const int*   ei    = (const int*)d_in[1];
    const int*   batch = (const int*)d_in[2];
    const float* W1    = (const float*)d_in[3];
    const float* g1    = (const float*)d_in[5];
    const float* bt1   = (const float*)d_in[6];
    const float* W2    = (const float*)d_in[7];
    const float* g2    = (const float*)d_in[9];
    const float* bt2   = (const float*)d_in[10];

    const int N = in_sizes[0] / 64;
    const int E = in_sizes[1] / 2;
    const int G = out_size / 64;

    const int* src = ei;
    const int* dst = ei + E;

    const int nb = (N + 127) >> 7;           // buckets of 128 dst nodes (nb <= 1024)
    int sb = 0; while ((1 << sb) < N) ++sb;  // bits to hold src id
    const unsigned int smask = (1u << sb) - 1u;

    ushort* tb        = (ushort*)d_ws;                       // N*64 bf16
    float* a          = (float*)(tb + (size_t)N * 64);       // N*64 f32
    int*   cs         = (int*)(a + (size_t)N * 64);          // E (CSR src ids)
    float* wf         = (float*)(cs + E);                    // E f32 edge weights
    unsigned int* eb  = (unsigned int*)(wf + E);             // E (bucketed packed edges)
    float* dis        = (float*)(eb + E);                    // N
    int*   rowptr     = (int*)(dis + N);                     // N+1
    int*   bktcnt     = rowptr + N + 1;                      // nb
    float* stats      = (float*)(bktcnt + nb);               // 256 (two sets of 128)
    int*   bktoff     = (int*)(stats + 256);                 // nb+1
    int*   gpos       = bktoff + nb + 1;                     // nb
    float* bnp        = (float*)(gpos + nb);                 // 128
    int*   gs         = (int*)(bnp + 128);                   // G+1

    float* out = (float*)d_out;

    const int mmBlocks = (N + 63) / 64;
    const int gaBlocks = (N + 3) / 4;
    const int pcBlocks = (E + CCHUNK - 1) / CCHUNK;

    // ---- CSR build (bucketed, write-local) ----
    hipMemsetAsync(bktcnt, 0, (size_t)(nb + 256) * sizeof(int), stream);  // bktcnt + both stats
    k_bhist<<<256, 256, 0, stream>>>(dst, E, nb, bktcnt);
    k_bscan<<<1, 256, 0, stream>>>(bktcnt, nb, N, bktoff, gpos, rowptr);
    k_partition<<<pcBlocks, 256, 0, stream>>>(src, dst, E, nb, sb, gpos, eb);
    k_row<<<nb, 256, 0, stream>>>(eb, bktoff, sb, N, dis, rowptr);
    k_csrfill<<<nb, 256, 0, stream>>>(eb, bktoff, rowptr, dis, sb, smask, N, cs, wf);
    k_gbound<<<(G + 256) / 256, 256, 0, stream>>>(batch, N, G, gs);

    // ---- layer 1 ----
    k_matmul64t<<<mmBlocks, 256, 0, stream>>>(x, W1, nullptr, N, tb);
    k_gather<<<gaBlocks, 256, 0, stream>>>(cs, wf, rowptr, dis, tb, N, a);
    k_stats<<<512, 256, 0, stream>>>(a, N, stats);
    k_bnparams<<<1, 64, 0, stream>>>(stats, g1, bt1, N, bnp);

    // ---- layer 2 (BN+ReLU of layer 1 fused into matmul input) ----
    k_matmul64t<<<mmBlocks, 256, 0, stream>>>(a, W2, bnp, N, tb);
    k_gather<<<gaBlocks, 256, 0, stream>>>(cs, wf, rowptr, dis, tb, N, a);
    k_stats<<<512, 256, 0, stream>>>(a, N, stats + 128);
    k_bnparams<<<1, 64, 0, stream>>>(stats + 128, g2, bt2, N, bnp);

    // ---- pool (BN+ReLU of layer 2 fused) ----
    k_pool2<<<(G + 3) / 4, 256, 0, stream>>>(a, bnp, gs, G, out);
}